// Round 6
// baseline (4950.156 us; speedup 1.0000x reference)
//
#include <hip/hip_runtime.h>
#include <stdint.h>
#include <math.h>

// ProbSparse attention, fp32-exact (round 10: 16 waves AND zero spill).
// Cross-round evidence: waves/CU is set by workgroup size alone (one wg/CU:
// NTH=512 -> 8 waves/24% in rounds 4/5/6/9; NTH=1024 -> 16 waves/48% in
// round 7). NTH=1024 carries a HARD 64-VGPR budget (rounds 7/8), so this
// round designs for 64: KPT=2 (acc[16][2]=32), ballot selection (~42 live),
// phase 4 in TWO row-groups of 8 with a full-width fp32 weight buffer
// wbuf[8][2048] = 64 KB (half of acc dies at each dump; peak ~45 live).
// V is read twice (L2-resident, cheap). Phase-1 d-chunk=4 keeps staging at
// 8 regs. Round-9 best: 4773 us @ VALU 50%, 8 waves; target ~3000-3700.

#define NB   16
#define LQ   2048
#define LK   2048
#define DIM  512
#define TOPK 512
#define ROWS 16
#define NTH  1024
#define KPT  2
#define RG   8      // rows per phase-4 group

static __device__ __forceinline__ uint32_t f2ord(float f) {
  uint32_t b = __float_as_uint(f);
  return (b & 0x80000000u) ? ~b : (b | 0x80000000u);   // order-preserving uint
}
static __device__ __forceinline__ float ord2f(uint32_t u) {
  uint32_t b = (u & 0x80000000u) ? (u ^ 0x80000000u) : ~u;
  return __uint_as_float(b);
}

__global__
__attribute__((amdgpu_flat_work_group_size(NTH, NTH)))
void psattn_kernel(const float* __restrict__ Q, const float* __restrict__ K,
                   const float* __restrict__ V,
                   float* __restrict__ O)
{
  // LDS map (16384 dwords = 64 KB total):
  //   [0 .. 8192)      Q tile 16x512 f32 (phase 1)                 [aliased]
  //   [0 .. 16384)     wbuf 8x2048 f32 per row-group (phase 4),
  //                    mbuf 8x512 (merge)                          [aliased]
  //   [16000 .. 16384) control (phases 2-3; fully consumed before the
  //                    first wbuf dump overwrites it)
  __shared__ __align__(16) uint32_t smem[16384];
  const int t    = threadIdx.x;
  const int lane = t & 63;
  const int wid  = t >> 6;                    // 16 waves
  const int b    = blockIdx.x >> 7;           // 128 q-tiles per batch
  const int q0   = (blockIdx.x & 127) * ROWS;

  const float* Qb = Q + ((size_t)b * LQ + q0) * DIM;
  const float* Kb = K + (size_t)b * LK * DIM;
  const float* Vb = V + (size_t)b * LK * DIM;

  // ---------------- stage Q tile (16x512 f32 = 32 KB) into LDS ----------------
  {
    const float4* s = (const float4*)Qb;
    float4*       d = (float4*)smem;
    #pragma unroll
    for (int i = 0; i < 2; ++i) d[i * NTH + t] = s[i * NTH + t];
  }
  __syncthreads();

  // ---------------- phase 1: scores acc[r][j] = Q[q0+r] . K[k0+j] ----------------
  const int k0 = t * KPT;                     // 2 consecutive keys per thread
  float acc[ROWS][KPT];                       // 32 VGPRs
  #pragma unroll
  for (int r = 0; r < ROWS; ++r) {
    #pragma unroll
    for (int j = 0; j < KPT; ++j) acc[r][j] = 0.f;
  }
  const float4* qs4 = (const float4*)smem;
  const float* kp = Kb + (size_t)k0 * DIM;    // row k0; row k0+1 at +DIM
  #pragma unroll 1
  for (int d = 0; d < DIM; d += 4) {
    float4 kv0 = *(const float4*)(kp);        // key k0,   dims d..d+3
    float4 kv1 = *(const float4*)(kp + DIM);  // key k0+1, dims d..d+3
    kp += 4;
    #pragma unroll
    for (int r = 0; r < ROWS; ++r) {
      float4 q = qs4[r * (DIM / 4) + (d >> 2)];   // wave-uniform LDS broadcast
      acc[r][0] += q.x * kv0.x + q.y * kv0.y + q.z * kv0.z + q.w * kv0.w;
      acc[r][1] += q.x * kv1.x + q.y * kv1.y + q.z * kv1.z + q.w * kv1.w;
    }
  }
  __syncthreads();   // Q region dead

  // ---------------- scale + orderable-uint transform (mask all-True) ----------------
  const float scale = 0.044194173824159216f;  // 1/sqrt(512)
  #pragma unroll
  for (int r = 0; r < ROWS; ++r) {
    #pragma unroll
    for (int j = 0; j < KPT; ++j) {
      float s = acc[r][j] * scale;
      acc[r][j] = __uint_as_float(f2ord(s));
    }
  }

  // control region in wbuf tail (dead before the first weight dump)
  uint32_t* ctl  = smem + 16000;
  uint32_t* lo   = ctl;                // [16]
  uint32_t* hi   = ctl + 16;           // [16]
  uint32_t* mid  = ctl + 32;           // [16]
  uint32_t* v512 = ctl + 48;           // [16] threshold (ordinal)
  uint32_t* need = ctl + 64;           // [16] # of ties to include
  float*    invZ = (float*)(ctl + 80); // [16]
  uint32_t* red  = ctl + 96;           // [16][8] packed counts / [16][16] floats

  if (t < ROWS) { lo[t] = 0u; hi[t] = 0xFFFFFFFFu; }
  __syncthreads();

  // ---------------- phase 2a: bisection for 512th-largest ordinal (exact) ----------------
  #pragma unroll 1
  for (int it = 0; it < 32; ++it) {
    if (t < ROWS) mid[t] = lo[t] + ((hi[t] - lo[t]) >> 1);
    __syncthreads();
    #pragma unroll
    for (int rp = 0; rp < ROWS / 2; ++rp) {
      const uint32_t m0 = mid[2 * rp], m1 = mid[2 * rp + 1];
      uint32_t c0 = 0, c1 = 0;
      #pragma unroll
      for (int j = 0; j < KPT; ++j) {
        c0 += (uint32_t)__popcll(__ballot(__float_as_uint(acc[2 * rp][j]) >= m0));
        c1 += (uint32_t)__popcll(__ballot(__float_as_uint(acc[2 * rp + 1][j]) >= m1));
      }
      if (lane == 0) red[wid * (ROWS / 2) + rp] = c0 | (c1 << 16);
    }
    __syncthreads();
    if (t < ROWS) {
      uint32_t cnt = 0;
      #pragma unroll
      for (int w = 0; w < 16; ++w) cnt += (red[w * (ROWS / 2) + (t >> 1)] >> (16 * (t & 1))) & 0xffffu;
      if (cnt >= TOPK) lo[t] = mid[t]; else hi[t] = mid[t];
    }
  }
  if (t < ROWS) v512[t] = lo[t];
  __syncthreads();

  // ---------------- phase 2b: strictly-greater count -> number of ties needed ----------------
  {
    #pragma unroll
    for (int rp = 0; rp < ROWS / 2; ++rp) {
      const uint32_t m0 = v512[2 * rp] + 1u, m1 = v512[2 * rp + 1] + 1u;
      uint32_t c0 = 0, c1 = 0;
      #pragma unroll
      for (int j = 0; j < KPT; ++j) {
        c0 += (uint32_t)__popcll(__ballot(__float_as_uint(acc[2 * rp][j]) >= m0));
        c1 += (uint32_t)__popcll(__ballot(__float_as_uint(acc[2 * rp + 1][j]) >= m1));
      }
      if (lane == 0) red[wid * (ROWS / 2) + rp] = c0 | (c1 << 16);
    }
    __syncthreads();
    if (t < ROWS) {
      uint32_t cnt = 0;
      #pragma unroll
      for (int w = 0; w < 16; ++w) cnt += (red[w * (ROWS / 2) + (t >> 1)] >> (16 * (t & 1))) & 0xffffu;
      need[t] = TOPK - cnt;           // >= 1 by construction
      lo[t] = 0xFFFFFFFFu;            // -1 (int)
      hi[t] = 2047u;
    }
    __syncthreads();
  }

  // ---------------- phase 2c: tie-break by lowest index (matches lax.top_k) ----------------
  #pragma unroll 1
  for (int it = 0; it < 11; ++it) {
    if (t < ROWS) mid[t] = (uint32_t)(((int)lo[t] + (int)hi[t]) >> 1);
    __syncthreads();
    #pragma unroll
    for (int rp = 0; rp < ROWS / 2; ++rp) {
      const uint32_t v0 = v512[2 * rp], v1 = v512[2 * rp + 1];
      const int mk0 = (int)mid[2 * rp], mk1 = (int)mid[2 * rp + 1];
      uint32_t c0 = 0, c1 = 0;
      #pragma unroll
      for (int j = 0; j < KPT; ++j) {
        c0 += (uint32_t)__popcll(__ballot((__float_as_uint(acc[2 * rp][j]) == v0) && (k0 + j <= mk0)));
        c1 += (uint32_t)__popcll(__ballot((__float_as_uint(acc[2 * rp + 1][j]) == v1) && (k0 + j <= mk1)));
      }
      if (lane == 0) red[wid * (ROWS / 2) + rp] = c0 | (c1 << 16);
    }
    __syncthreads();
    if (t < ROWS) {
      uint32_t cnt = 0;
      #pragma unroll
      for (int w = 0; w < 16; ++w) cnt += (red[w * (ROWS / 2) + (t >> 1)] >> (16 * (t & 1))) & 0xffffu;
      if (cnt >= need[t]) hi[t] = mid[t]; else lo[t] = mid[t];
    }
  }
  __syncthreads();   // publish final kcut (= hi[r])

  // ---------------- phase 3: weights = exp(s - t) for selected, + Z (fused reduce) ----------------
  {
    float* redf = (float*)red;     // [16][16]
    #pragma unroll
    for (int r = 0; r < ROWS; ++r) {
      uint32_t vr = v512[r];
      int      kc = (int)hi[r];
      float    tr = ord2f(vr);
      float    zr = 0.f;
      #pragma unroll
      for (int j = 0; j < KPT; ++j) {
        uint32_t u = __float_as_uint(acc[r][j]);
        bool sel = (u > vr) || ((u == vr) && (k0 + j <= kc));
        float s = ord2f(u);
        float w = 0.f;
        if (sel && (s > -INFINITY)) w = __expf(s - tr);
        acc[r][j] = w;
        zr += w;
      }
      #pragma unroll
      for (int sft = 32; sft >= 1; sft >>= 1) zr += __shfl_xor(zr, sft, 64);
      if (lane == 0) redf[wid * ROWS + r] = zr;
    }
    __syncthreads();
    if (t < ROWS) {
      float z = 0.f;
      #pragma unroll
      for (int w = 0; w < 16; ++w) z += redf[w * ROWS + t];
      invZ[t] = 1.f / z;
    }
    __syncthreads();
  }

  // fold 1/Z into the weights; then ctl region is dead
  #pragma unroll
  for (int r = 0; r < ROWS; ++r) {
    float iz = invZ[r];
    acc[r][0] *= iz;
    acc[r][1] *= iz;
  }
  __syncthreads();   // all invZ reads done before wbuf dump overwrites ctl

  // ---------------- phase 4: out = W @ V in two row-groups of 8 ----------------
  // wbuf holds the FULL 2048-key normalized weight rows for one group (64 KB);
  // after the group-g dump, acc rows [g*8, g*8+8) are dead.
  float* wbuf = (float*)smem;       // [8][2048] fp32 = 64 KB
  const int dd = t & 511;           // this thread's dim column
  const int kh = t >> 9;            // this thread's key half (wave-uniform)

  #pragma unroll
  for (int g = 0; g < 2; ++g) {     // FULL unroll: acc indices compile-time
    // dump: every thread writes its 2 keys for the 8 rows of this group
    #pragma unroll
    for (int rr = 0; rr < RG; ++rr)
      *(float2*)&wbuf[rr * 2048 + 2 * t] =
          make_float2(acc[g * RG + rr][0], acc[g * RG + rr][1]);
    __syncthreads();

    float outp[RG];
    #pragma unroll
    for (int rr = 0; rr < RG; ++rr) outp[rr] = 0.f;

    const float* vb = Vb + (size_t)(kh * 1024) * DIM + dd;
    const float* wb = wbuf + kh * 1024;
    float vc[4];
    #pragma unroll
    for (int m = 0; m < 4; ++m) vc[m] = vb[(size_t)m * DIM];
    #pragma unroll 1
    for (int kk = 0; kk < 1024; kk += 4) {
      float vn[4];
      const bool pf = (kk + 4) < 1024;
      if (pf) {
        #pragma unroll
        for (int m = 0; m < 4; ++m) vn[m] = vb[(size_t)(kk + 4 + m) * DIM];
      }
      #pragma unroll
      for (int rr = 0; rr < RG; ++rr) {
        float4 w4 = *(const float4*)&wb[rr * 2048 + kk];  // uniform LDS broadcast
        outp[rr] += w4.x * vc[0] + w4.y * vc[1] + w4.z * vc[2] + w4.w * vc[3];
      }
      if (pf) { vc[0] = vn[0]; vc[1] = vn[1]; vc[2] = vn[2]; vc[3] = vn[3]; }
    }
    __syncthreads();   // wbuf reads done; reuse as merge buffer

    // merge the two key-halves, store rows of this group
    float* mbuf = (float*)smem;     // [8][512] fp32 = 16 KB
    if (kh == 1) {
      #pragma unroll
      for (int rr = 0; rr < RG; ++rr) mbuf[rr * 512 + dd] = outp[rr];
    }
    __syncthreads();
    if (kh == 0) {
      #pragma unroll
      for (int rr = 0; rr < RG; ++rr)
        O[((size_t)b * LQ + q0 + g * RG + rr) * DIM + dd] = outp[rr] + mbuf[rr * 512 + dd];
    }
    __syncthreads();   // mbuf consumed before next group's dump
  }
}

extern "C" void kernel_launch(void* const* d_in, const int* in_sizes, int n_in,
                              void* d_out, int out_size, void* d_ws, size_t ws_size,
                              hipStream_t stream) {
  const float* Q = (const float*)d_in[0];
  const float* K = (const float*)d_in[1];
  const float* V = (const float*)d_in[2];
  float*       O = (float*)d_out;
  dim3 grid(NB * (LQ / ROWS));   // 2048 workgroups
  dim3 block(NTH);
  hipLaunchKernelGGL(psattn_kernel, grid, block, 0, stream, Q, K, V, O);
  (void)in_sizes; (void)n_in; (void)out_size; (void)d_ws; (void)ws_size;
}